// Round 1
// baseline (38.320 us; speedup 1.0000x reference)
//
#include <hip/hip_runtime.h>

// DUC depth-to-space: x (64, 6*8*8, 32, 32) f32 -> out (64, 6, 304, 304) f32
// out[b,c,i*8+p, j*8+q] = x[b, c*64 + p*8 + q, i, j]; rows/cols 256..303 are zero.
//
// One wave (64 lanes) per output row (b,c,oh). Lane l writes float4 at ow=4l.
// For oh<256: q0=(l&1)*4, j=l>>1 -> each of the 4 gather loads is dense across
// the wave (two 128B segments per load instruction). Lanes 0..11 also zero the
// 48-col right tail. For oh>=256: pure zero row (76 float4).

#define CLASSES 6
#define RZ 8
#define OUT_HW 304
#define IN_HW 32
#define B_ 64
#define CIN (CLASSES * RZ * RZ)   // 384

__global__ __launch_bounds__(256) void duc_kernel(const float* __restrict__ x,
                                                  float* __restrict__ out) {
    const int gid  = blockIdx.x * blockDim.x + threadIdx.x;
    const int wave = gid >> 6;
    const int lane = gid & 63;

    // wave -> (b, c, oh)
    const int oh = wave % OUT_HW;
    const int bc = wave / OUT_HW;           // b*6 + c
    const int c  = bc % CLASSES;
    const int b  = bc / CLASSES;

    float4* outrow = (float4*)(out + ((size_t)bc * OUT_HW + oh) * OUT_HW);

    const float4 zero4 = make_float4(0.f, 0.f, 0.f, 0.f);

    if (oh < 256) {
        const int i  = oh >> 3;
        const int p  = oh & 7;
        const int q0 = (lane & 1) * 4;
        const int j  = lane >> 1;

        // base channel = c*64 + p*8 ; element (i, j) of each 32x32 map
        const float* inbase =
            x + ((size_t)(b * CIN + c * (RZ * RZ) + p * RZ) * (IN_HW * IN_HW))
              + i * IN_HW + j;

        float4 v;
        v.x = inbase[(q0 + 0) * (IN_HW * IN_HW)];
        v.y = inbase[(q0 + 1) * (IN_HW * IN_HW)];
        v.z = inbase[(q0 + 2) * (IN_HW * IN_HW)];
        v.w = inbase[(q0 + 3) * (IN_HW * IN_HW)];

        outrow[lane] = v;                 // interior: cols 0..255
        if (lane < 12) outrow[64 + lane] = zero4;   // right border: cols 256..303
    } else {
        // bottom border rows: 304 floats = 76 float4 of zeros
        outrow[lane] = zero4;
        if (lane < 12) outrow[64 + lane] = zero4;
    }
}

extern "C" void kernel_launch(void* const* d_in, const int* in_sizes, int n_in,
                              void* d_out, int out_size, void* d_ws, size_t ws_size,
                              hipStream_t stream) {
    const float* x = (const float*)d_in[0];
    float* out = (float*)d_out;

    const int rows = B_ * CLASSES * OUT_HW;      // one wave per row
    const int threads = 256;                     // 4 waves per block
    const int blocks = (rows * 64) / threads;    // 116736*64/256 = 29184, exact

    duc_kernel<<<blocks, threads, 0, stream>>>(x, out);
}